// Round 1
// baseline (661.050 us; speedup 1.0000x reference)
//
#include <hip/hip_runtime.h>

#define TT   2048
#define CC   256
#define LL   256
#define SS   513          // 2*LL+1
#define BLK  576          // 9 waves of 64
#define NEGF (-1e30f)
#define EPSF (1e-7f)
#define LN2F (0.69314718055994531f)

__launch_bounds__(BLK, 1)
__global__ void ctc_fwd_kernel(const int* __restrict__ y_true,
                               const float* __restrict__ y_pred,
                               float* __restrict__ out)
{
    // double-buffered alpha (log2 domain), 2 leading NEG pads per buffer
    __shared__ float shbuf[2][SS + 2];
    __shared__ float fin[2];

    const int b = blockIdx.x;
    const int s = threadIdx.x;
    const bool active = (s < SS);

    const int blank = CC - 1;
    int  zs = blank;
    bool allow2 = false;
    if (active && (s & 1)) {
        zs = y_true[b * LL + ((s - 1) >> 1)];
        const int zm2 = (s >= 3) ? y_true[b * LL + ((s - 3) >> 1)] : -1;
        allow2 = (zs != blank) && (zs != zm2);
    }
    const float* pt = y_pred + ((size_t)b * TT) * CC + zs;

    // init the two NEG pads of both buffers (indices 0,1)
    if (s < 2) { shbuf[0][s] = NEGF; shbuf[1][s] = NEGF; }

    float beta = NEGF;
    float pf[8];             // rolling prefetch buffer, statically indexed
    if (active) {
        const float p0 = pt[0];
        #pragma unroll
        for (int j = 0; j < 8; ++j)
            pf[j] = pt[(size_t)(1 + j) * CC];
        // alpha0 in log2 domain
        beta = (s < 2) ? __builtin_amdgcn_logf(p0 + EPSF) : NEGF;
        shbuf[0][2 + s] = beta;
    }
    __syncthreads();

    int cur = 0;
    int t = 1;
    for (int chunk = 0; chunk < 256; ++chunk) {
        #pragma unroll
        for (int j = 0; j < 8; ++j, ++t) {
            if (t < TT) {                     // block-uniform guard
                if (active) {
                    const float pc = pf[j];
                    const int tp = t + 8;     // prefetch 8 steps ahead
                    if (tp < TT) pf[j] = pt[(size_t)tp * CC];

                    const float lp  = __builtin_amdgcn_logf(pc + EPSF);
                    const float b1  = shbuf[cur][1 + s];
                    const float b2r = shbuf[cur][s];
                    const float b2  = allow2 ? b2r : NEGF;

                    const float m   = fmaxf(beta, fmaxf(b1, b2));
                    const float sum = __builtin_amdgcn_exp2f(beta - m)
                                    + __builtin_amdgcn_exp2f(b1  - m)
                                    + __builtin_amdgcn_exp2f(b2  - m);
                    beta = lp + m + __builtin_amdgcn_logf(sum);
                    shbuf[cur ^ 1][2 + s] = beta;
                }
                __syncthreads();
                cur ^= 1;
            }
        }
    }

    if (s == SS - 1) fin[0] = beta;
    if (s == SS - 2) fin[1] = beta;
    __syncthreads();
    if (s == 0) {
        const float x = fin[0], y = fin[1];
        const float m = fmaxf(x, y);
        const float ll2 = m + __builtin_amdgcn_logf(
                                 __builtin_amdgcn_exp2f(x - m) +
                                 __builtin_amdgcn_exp2f(y - m));
        out[b] = -LN2F * ll2;   // back to natural-log domain
    }
}

extern "C" void kernel_launch(void* const* d_in, const int* in_sizes, int n_in,
                              void* d_out, int out_size, void* d_ws, size_t ws_size,
                              hipStream_t stream)
{
    const int*   y_true = (const int*)d_in[0];
    const float* y_pred = (const float*)d_in[1];
    float*       out    = (float*)d_out;
    const int B = in_sizes[0] / LL;   // 32
    ctc_fwd_kernel<<<B, BLK, 0, stream>>>(y_true, y_pred, out);
}